// Round 1
// baseline (378.699 us; speedup 1.0000x reference)
//
#include <hip/hip_runtime.h>
#include <hip/hip_cooperative_groups.h>
#include <stdint.h>

namespace cg = cooperative_groups;

#define LOG2E  1.44269504088896f
#define QSCALE (0.125f * LOG2E)   // folded into Q: sacc is already the exp2 argument

typedef float    f32x4_t  __attribute__((ext_vector_type(4)));
typedef float    f32x16_t __attribute__((ext_vector_type(16)));
typedef _Float16 f16x8_t  __attribute__((ext_vector_type(8)));
typedef _Float16 f16x2_t  __attribute__((ext_vector_type(2)));

#if __has_builtin(__builtin_amdgcn_exp2f)
#define EXP2F(x) __builtin_amdgcn_exp2f(x)
#else
#define EXP2F(x) exp2f(x)
#endif

__device__ __forceinline__ float rowsum2(f16x2_t p, float acc) {
#if __has_builtin(__builtin_amdgcn_fdot2)
  return __builtin_amdgcn_fdot2(p, (f16x2_t){(_Float16)1.0f, (_Float16)1.0f}, acc, false);
#else
  return acc + (float)p[0] + (float)p[1];
#endif
}

// ---------------- staging regs (global -> reg -> LDS) ----------------
struct SRegs {
  uint4 kk0, kk1, vv0, vv1;   // WS16 path
  f32x4_t k0, k1, k2, k3;     // fallback K
  float vlo[8], vhi[8];       // fallback V
};

template <bool WS16>
__device__ __forceinline__ void stage_load(SRegs& r, int tid, size_t hoff, int kbase,
                                           const _Float16* __restrict__ Kh,
                                           const _Float16* __restrict__ Vth,
                                           const float* __restrict__ Kg,
                                           const float* __restrict__ Vg) {
  if constexpr (WS16) {
    const _Float16* kp = Kh + hoff + (size_t)(kbase + (tid >> 2)) * 64 + (tid & 3) * 16;
    r.kk0 = *(const uint4*)(kp);
    r.kk1 = *(const uint4*)(kp + 8);
    const _Float16* vp = Vth + hoff + (size_t)(tid >> 2) * 4096 + kbase + (tid & 3) * 16;
    r.vv0 = *(const uint4*)(vp);
    r.vv1 = *(const uint4*)(vp + 8);
  } else {
    const float* kp = Kg + hoff + (size_t)(kbase + (tid >> 2)) * 64 + (tid & 3) * 16;
    r.k0 = *(const f32x4_t*)(kp + 0);
    r.k1 = *(const f32x4_t*)(kp + 4);
    r.k2 = *(const f32x4_t*)(kp + 8);
    r.k3 = *(const f32x4_t*)(kp + 12);
    const float* vp = Vg + hoff + (size_t)(kbase + (tid >> 5) * 8) * 64 + (tid & 31);
#pragma unroll
    for (int j = 0; j < 8; ++j) {
      r.vlo[j] = vp[(size_t)j * 64];
      r.vhi[j] = vp[(size_t)j * 64 + 32];
    }
  }
}

template <bool WS16>
__device__ __forceinline__ void stage_write(const SRegs& r, int tid,
                                            _Float16* __restrict__ Ksb,
                                            _Float16* __restrict__ Vtb) {
  if constexpr (WS16) {
    *(uint4*)&Ksb[(tid >> 2) * 72 + (tid & 3) * 16]     = r.kk0;
    *(uint4*)&Ksb[(tid >> 2) * 72 + (tid & 3) * 16 + 8] = r.kk1;
    *(uint4*)&Vtb[(tid >> 2) * 72 + (tid & 3) * 16]     = r.vv0;
    *(uint4*)&Vtb[(tid >> 2) * 72 + (tid & 3) * 16 + 8] = r.vv1;
  } else {
    union { _Float16 h[8]; uint4 q; } A, B;
#pragma unroll
    for (int j = 0; j < 4; ++j) {
      A.h[j] = (_Float16)r.k0[j];  A.h[4 + j] = (_Float16)r.k1[j];
      B.h[j] = (_Float16)r.k2[j];  B.h[4 + j] = (_Float16)r.k3[j];
    }
    *(uint4*)&Ksb[(tid >> 2) * 72 + (tid & 3) * 16]     = A.q;
    *(uint4*)&Ksb[(tid >> 2) * 72 + (tid & 3) * 16 + 8] = B.q;
    union { _Float16 h[8]; uint4 q; } C, D;
#pragma unroll
    for (int j = 0; j < 8; ++j) { C.h[j] = (_Float16)r.vlo[j]; D.h[j] = (_Float16)r.vhi[j]; }
    *(uint4*)&Vtb[(tid & 31) * 72 + (tid >> 5) * 8]        = C.q;
    *(uint4*)&Vtb[((tid & 31) + 32) * 72 + (tid >> 5) * 8] = D.q;
  }
}

// ---------------- fallback prep kernels (used only if coop launch fails) ----------------
__global__ void mask_scan_kernel(const float* __restrict__ m, int* __restrict__ flag) {
  const float* p = m + (size_t)blockIdx.x * 8192 + (size_t)threadIdx.x * 4;
  unsigned acc = 0;
#pragma unroll
  for (int i = 0; i < 8; ++i) {
    f32x4_t v = *(const f32x4_t*)(p + (size_t)i * 1024);
    acc |= __float_as_uint(v[0]) | __float_as_uint(v[1]) |
           __float_as_uint(v[2]) | __float_as_uint(v[3]);
  }
  acc &= 0x7fffffffu;
  if (acc) atomicOr(flag, 1);
}

__global__ void convert_k_kernel(const float* __restrict__ K, _Float16* __restrict__ Kh) {
  const size_t idx = ((size_t)blockIdx.x * 256 + threadIdx.x) * 8;
  f32x4_t a = *(const f32x4_t*)(K + idx);
  f32x4_t b = *(const f32x4_t*)(K + idx + 4);
  union { _Float16 h[8]; uint4 q; } U;
#pragma unroll
  for (int j = 0; j < 4; ++j) { U.h[j] = (_Float16)a[j]; U.h[4 + j] = (_Float16)b[j]; }
  *(uint4*)(Kh + idx) = U.q;
}

__global__ void transpose_v_kernel(const float* __restrict__ V, _Float16* __restrict__ Vth) {
  __shared__ __align__(16) _Float16 T[64 * 72];
  const int tid  = threadIdx.x;
  const int head = blockIdx.x >> 6;
  const int st   = blockIdx.x & 63;
  const size_t hoff = (size_t)head * 4096 * 64;

  const int sl    = tid >> 2;
  const int fbase = (tid & 3) * 16;
  const float* src = V + hoff + (size_t)(st * 64 + sl) * 64 + fbase;
#pragma unroll
  for (int c = 0; c < 4; ++c) {
    f32x4_t a = *(const f32x4_t*)(src + c * 4);
#pragma unroll
    for (int j = 0; j < 4; ++j) T[(fbase + c * 4 + j) * 72 + sl] = (_Float16)a[j];
  }
  __syncthreads();
  const int feat = tid >> 2;
  const int sb   = (tid & 3) * 16;
  uint4 r0 = *(const uint4*)&T[feat * 72 + sb];
  uint4 r1 = *(const uint4*)&T[feat * 72 + sb + 8];
  _Float16* dst = Vth + hoff + (size_t)feat * 4096 + st * 64 + sb;
  *(uint4*)(dst)     = r0;
  *(uint4*)(dst + 8) = r1;
}

// ---------------- fused SDPA ----------------
// FUSED: phase 0 (mask scan + K f32->f16 + V transpose) runs in this kernel, then grid.sync().
// sigma trick: reading K rows through sig(n)=swap(bit2,bit3 of n) during S^T=K.Q^T
// relabels C-rows so that PV A-fragments are lane-local sacc regs (no P LDS round-trip).
template <bool WS16, bool FUSED>
__launch_bounds__(256, 2)
__global__ void sdpa_kernel(const float* __restrict__ Qg, const float* __restrict__ Kg,
                            const float* __restrict__ Vg, const float* __restrict__ Mg,
                            _Float16* __restrict__ Kh, _Float16* __restrict__ Vth,
                            float* __restrict__ Og, int* __restrict__ flag) {
  __shared__ __align__(16) _Float16 Ks[2][64 * 72];   // [buf][key][feat]
  __shared__ __align__(16) _Float16 Vt[2][64 * 72];   // [buf][feat][key]

  const int tid = threadIdx.x;
  const int bid = blockIdx.x;

  if constexpr (FUSED) {
    // ---- phase 0a: mask all-zero scan (512 blocks x 256 thr x 128 floats) ----
    {
      const float* p = Mg + (size_t)bid * 32768 + (size_t)tid * 4;
      unsigned acc = 0;
#pragma unroll
      for (int i = 0; i < 32; ++i) {
        f32x4_t v = *(const f32x4_t*)(p + (size_t)i * 1024);
        acc |= __float_as_uint(v[0]) | __float_as_uint(v[1]) |
               __float_as_uint(v[2]) | __float_as_uint(v[3]);
      }
      if (acc & 0x7fffffffu) atomicOr(flag, 1);
    }
    if constexpr (WS16) {
      // ---- phase 0b: K f32->f16 (4 x 8 elems per thread) ----
      {
        const size_t g = (size_t)bid * 256 + tid;
#pragma unroll
        for (int i = 0; i < 4; ++i) {
          const size_t idx = (g + (size_t)i * 131072) * 8;
          f32x4_t a = *(const f32x4_t*)(Kg + idx);
          f32x4_t b = *(const f32x4_t*)(Kg + idx + 4);
          union { _Float16 h[8]; uint4 q; } U;
#pragma unroll
          for (int j = 0; j < 4; ++j) { U.h[j] = (_Float16)a[j]; U.h[4 + j] = (_Float16)b[j]; }
          *(uint4*)(Kh + idx) = U.q;
        }
      }
      // ---- phase 0c: V transpose to [head][feat][seq], 2 tiles per block ----
      {
        _Float16* T = &Ks[0][0];
        const int sl    = tid >> 2;
        const int fbase = (tid & 3) * 16;
        const int feat  = tid >> 2;
        const int sb    = (tid & 3) * 16;
#pragma unroll 1
        for (int tt = 0; tt < 2; ++tt) {
          const int t    = bid * 2 + tt;
          const int head = t >> 6;
          const int st   = t & 63;
          const size_t vhoff = (size_t)head * 4096 * 64;
          const float* src = Vg + vhoff + (size_t)(st * 64 + sl) * 64 + fbase;
          __syncthreads();   // prior tile's T reads complete
#pragma unroll
          for (int c = 0; c < 4; ++c) {
            f32x4_t a = *(const f32x4_t*)(src + c * 4);
#pragma unroll
            for (int j = 0; j < 4; ++j) T[(fbase + c * 4 + j) * 72 + sl] = (_Float16)a[j];
          }
          __syncthreads();
          uint4 t0 = *(const uint4*)&T[feat * 72 + sb];
          uint4 t1 = *(const uint4*)&T[feat * 72 + sb + 8];
          _Float16* dst = Vth + vhoff + (size_t)feat * 4096 + st * 64 + sb;
          *(uint4*)(dst)     = t0;
          *(uint4*)(dst + 8) = t1;
        }
      }
    }
    cg::this_grid().sync();   // device-scope fence: Kh/Vth/flag visible to all blocks
  }

  const bool has_mask = (*(volatile const int*)flag) != 0;

  const int hh   = ((bid & 7) << 1) | ((bid >> 3) & 1);   // 2 heads per XCD
  const int qt   = bid >> 4;
  const int w    = tid >> 6;
  const int lane = tid & 63;
  const int n    = lane & 31;
  const int h2   = lane >> 5;
  const int sig  = (n & 0x13) | ((n >> 1) & 4) | ((n << 1) & 8);  // swap bits 2,3
  const size_t hoff = (size_t)hh * 4096 * 64;
  const int qcol = qt * 128 + w * 32 + n;

  // ---- Q B-fragment straight from f32 (read once per block; no pre-convert pass) ----
  f16x8_t qf[4];
  {
    const float* qp = Qg + hoff + (size_t)qcol * 64 + 8 * h2;
#pragma unroll
    for (int kh = 0; kh < 4; ++kh) {
      f32x4_t a = *(const f32x4_t*)(qp + kh * 16);
      f32x4_t b = *(const f32x4_t*)(qp + kh * 16 + 4);
      union { _Float16 h[8]; f16x8_t v; } U;
#pragma unroll
      for (int j = 0; j < 4; ++j) { U.h[j] = (_Float16)(a[j] * QSCALE); U.h[4 + j] = (_Float16)(b[j] * QSCALE); }
      qf[kh] = U.v;
    }
  }

  f32x16_t o0 = {0.f,0.f,0.f,0.f,0.f,0.f,0.f,0.f,0.f,0.f,0.f,0.f,0.f,0.f,0.f,0.f};
  f32x16_t o1 = o0;
  float lacc = 0.0f;

  _Float16* const Ks0 = &Ks[0][0];
  _Float16* const Ks1 = &Ks[1][0];
  _Float16* const Vt0 = &Vt[0][0];
  _Float16* const Vt1 = &Vt[1][0];

  // ---- prologue: stage tile 0 into buffer 0 ----
  SRegs r;
  stage_load<WS16>(r, tid, hoff, 0, Kh, Vth, Kg, Vg);
  stage_write<WS16>(r, tid, Ks0, Vt0);
  __syncthreads();

  // ---- main loop: double-buffered, ONE barrier per K-tile.
  // iter t: issue global loads for t+1; compute from buf[t&1]; write buf[(t+1)&1]; sync.
#pragma unroll 2
  for (int kt = 0; kt < 64; ++kt) {
    const int kbase = kt * 64;
    _Float16* const Ksc = (kt & 1) ? Ks1 : Ks0;
    _Float16* const Vtc = (kt & 1) ? Vt1 : Vt0;
    _Float16* const Ksn = (kt & 1) ? Ks0 : Ks1;
    _Float16* const Vtn = (kt & 1) ? Vt0 : Vt1;

    if (kt < 63) stage_load<WS16>(r, tid, hoff, kbase + 64, Kh, Vth, Kg, Vg);

    // mask tile: element (kb, reg=8a+4b+c) -> key kb*32 + 16a + 8*h2 + 4b + c
    f32x4_t mk[2][2][2];
    if (has_mask) {
      const float* mp = Mg + (size_t)qcol * 4096 + kbase + 8 * h2;
#pragma unroll
      for (int kb = 0; kb < 2; ++kb)
#pragma unroll
        for (int a = 0; a < 2; ++a)
#pragma unroll
          for (int b = 0; b < 2; ++b)
            mk[kb][a][b] = *(const f32x4_t*)(mp + kb * 32 + 16 * a + 4 * b);
    }

#pragma unroll
    for (int kb = 0; kb < 2; ++kb) {
      // ---- S^T = K.Q^T with sigma-permuted A rows ----
      f32x16_t acc = {0.f,0.f,0.f,0.f,0.f,0.f,0.f,0.f,0.f,0.f,0.f,0.f,0.f,0.f,0.f,0.f};
#pragma unroll
      for (int kh = 0; kh < 4; ++kh) {
        const f16x8_t ka = *(const f16x8_t*)&Ksc[(kb * 32 + sig) * 72 + kh * 16 + 8 * h2];
        acc = __builtin_amdgcn_mfma_f32_32x32x16_f16(ka, qf[kh], acc, 0, 0, 0);
      }
      // ---- softmax + PV, lane-local: frag f = 2*kb + a uses regs 8a..8a+7 ----
#pragma unroll
      for (int a = 0; a < 2; ++a) {
        union { _Float16 h[8]; f16x8_t v; f16x2_t p2[4]; } F;
#pragma unroll
        for (int idx = 0; idx < 8; ++idx) {
          float x = acc[8 * a + idx];
          if (has_mask) x = __builtin_fmaf(mk[kb][a][idx >> 2][idx & 3], LOG2E, x);
          F.h[idx] = (_Float16)EXP2F(x);
        }
#pragma unroll
        for (int t = 0; t < 4; ++t) lacc = rowsum2(F.p2[t], lacc);
        const int f = kb * 2 + a;
        const f16x8_t v0 = *(const f16x8_t*)&Vtc[n * 72 + f * 16 + 8 * h2];
        o0 = __builtin_amdgcn_mfma_f32_32x32x16_f16(F.v, v0, o0, 0, 0, 0);
        const f16x8_t v1 = *(const f16x8_t*)&Vtc[(32 + n) * 72 + f * 16 + 8 * h2];
        o1 = __builtin_amdgcn_mfma_f32_32x32x16_f16(F.v, v1, o1, 0, 0, 0);
      }
    }

    if (kt < 63) {
      stage_write<WS16>(r, tid, Ksn, Vtn);
      __syncthreads();
    }
  }

  // ---- epilogue: l per q-column, normalize, store ----
  float lq = lacc + __shfl_xor(lacc, 32);
  float* op = Og + hoff;
#pragma unroll
  for (int r2 = 0; r2 < 4; ++r2) {
#pragma unroll
    for (int rr = 0; rr < 4; ++rr) {
      const int reg  = r2 * 4 + rr;
      const int qrow = rr + 8 * r2 + 4 * h2;      // C/D row mapping (m74/m101)
      float lr  = __shfl(lq, qrow);
      float inv = 1.0f / lr;
      const size_t row = (size_t)(qt * 128 + w * 32 + qrow) * 64;
      op[row + n]      = o0[reg] * inv;
      op[row + 32 + n] = o1[reg] * inv;
    }
  }
}

extern "C" void kernel_launch(void* const* d_in, const int* in_sizes, int n_in,
                              void* d_out, int out_size, void* d_ws, size_t ws_size,
                              hipStream_t stream) {
  const float* Q = (const float*)d_in[0];
  const float* K = (const float*)d_in[1];
  const float* V = (const float*)d_in[2];
  const float* M = (const float*)d_in[3];
  float* O = (float*)d_out;

  const size_t NELEM = (size_t)16 * 4096 * 64;          // 4M per tensor
  const size_t need  = 256 + 2 * NELEM * sizeof(_Float16);
  int* flag = (int*)d_ws;
  const bool ws16 = (ws_size >= need);
  _Float16* Kh  = ws16 ? (_Float16*)((char*)d_ws + 256) : nullptr;
  _Float16* Vth = ws16 ? Kh + NELEM : nullptr;

  hipMemsetAsync(flag, 0, sizeof(int), stream);

  const float* q = Q; const float* k = K; const float* v = V; const float* m = M;
  _Float16* kh = Kh; _Float16* vth = Vth; float* o = O; int* fl = flag;
  void* args[] = {&q, &k, &v, &m, &kh, &vth, &o, &fl};

  hipError_t err;
  if (ws16)
    err = hipLaunchCooperativeKernel((void*)&sdpa_kernel<true, true>,
                                     dim3(512), dim3(256), args, 0, stream);
  else
    err = hipLaunchCooperativeKernel((void*)&sdpa_kernel<false, true>,
                                     dim3(512), dim3(256), args, 0, stream);

  if (err != hipSuccess) {
    // sequential fallback (no grid sync inside the kernel)
    mask_scan_kernel<<<2048, 256, 0, stream>>>(M, flag);
    if (ws16) {
      convert_k_kernel<<<2048, 256, 0, stream>>>(K, Kh);
      transpose_v_kernel<<<1024, 256, 0, stream>>>(V, Vth);
      sdpa_kernel<true, false><<<512, 256, 0, stream>>>(Q, K, V, M, Kh, Vth, O, flag);
    } else {
      sdpa_kernel<false, false><<<512, 256, 0, stream>>>(Q, K, V, M, nullptr, nullptr, O, flag);
    }
  }
}

// Round 2
// 238.235 us; speedup vs baseline: 1.5896x; 1.5896x over previous
//
#include <hip/hip_runtime.h>
#include <stdint.h>

#define LOG2E  1.44269504088896f
#define QSCALE (0.125f * LOG2E)   // folded into Q: sacc is already the exp2 argument

typedef float    f32x4_t  __attribute__((ext_vector_type(4)));
typedef float    f32x16_t __attribute__((ext_vector_type(16)));
typedef _Float16 f16x8_t  __attribute__((ext_vector_type(8)));
typedef _Float16 f16x2_t  __attribute__((ext_vector_type(2)));

#if __has_builtin(__builtin_amdgcn_exp2f)
#define EXP2F(x) __builtin_amdgcn_exp2f(x)
#else
#define EXP2F(x) exp2f(x)
#endif

__device__ __forceinline__ float rowsum2(f16x2_t p, float acc) {
#if __has_builtin(__builtin_amdgcn_fdot2)
  return __builtin_amdgcn_fdot2(p, (f16x2_t){(_Float16)1.0f, (_Float16)1.0f}, acc, false);
#else
  return acc + (float)p[0] + (float)p[1];
#endif
}

// ---------------- fused prep: mask scan + K f32->f16 + V transpose ----------------
// grid 2048 x 256. Blocks 0..2047: mask chunk + K-convert chunk. Blocks 0..1023: one V tile.
__global__ void prep_kernel(const float* __restrict__ M, const float* __restrict__ K,
                            const float* __restrict__ V, _Float16* __restrict__ Kh,
                            _Float16* __restrict__ Vth, int* __restrict__ flag) {
  __shared__ __align__(16) _Float16 T[64 * 72];
  const int tid = threadIdx.x;
  const int bid = blockIdx.x;

  // -- mask all-zero scan (67 MB total) --
  {
    const float* p = M + (size_t)bid * 8192 + (size_t)tid * 4;
    unsigned acc = 0;
#pragma unroll
    for (int i = 0; i < 8; ++i) {
      f32x4_t v = *(const f32x4_t*)(p + (size_t)i * 1024);
      acc |= __float_as_uint(v[0]) | __float_as_uint(v[1]) |
             __float_as_uint(v[2]) | __float_as_uint(v[3]);
    }
    if (acc & 0x7fffffffu) atomicOr(flag, 1);
  }

  if (Kh != nullptr) {
    // -- K f32 -> f16 (8 elems/thread) --
    {
      const size_t idx = ((size_t)bid * 256 + tid) * 8;
      f32x4_t a = *(const f32x4_t*)(K + idx);
      f32x4_t b = *(const f32x4_t*)(K + idx + 4);
      union { _Float16 h[8]; uint4 q; } U;
#pragma unroll
      for (int j = 0; j < 4; ++j) { U.h[j] = (_Float16)a[j]; U.h[4 + j] = (_Float16)b[j]; }
      *(uint4*)(Kh + idx) = U.q;
    }
    // -- V transpose to [head][feat][seq] f16, one 64x64 tile per block (blocks 0..1023) --
    if (bid < 1024) {
      const int head = bid >> 6;
      const int st   = bid & 63;
      const size_t hoff = (size_t)head * 4096 * 64;
      const int sl    = tid >> 2;
      const int fbase = (tid & 3) * 16;
      const float* src = V + hoff + (size_t)(st * 64 + sl) * 64 + fbase;
#pragma unroll
      for (int c = 0; c < 4; ++c) {
        f32x4_t a = *(const f32x4_t*)(src + c * 4);
#pragma unroll
        for (int j = 0; j < 4; ++j) T[(fbase + c * 4 + j) * 72 + sl] = (_Float16)a[j];
      }
      __syncthreads();
      const int feat = tid >> 2;
      const int sb   = (tid & 3) * 16;
      uint4 r0 = *(const uint4*)&T[feat * 72 + sb];
      uint4 r1 = *(const uint4*)&T[feat * 72 + sb + 8];
      _Float16* dst = Vth + hoff + (size_t)feat * 4096 + st * 64 + sb;
      *(uint4*)(dst)     = r0;
      *(uint4*)(dst + 8) = r1;
    }
  }
}

// ---------------- SDPA core (round-0 proven structure) ----------------
// sigma trick: reading K rows through sig(n)=swap(bit2,bit3 of n) during S^T=K.Q^T
// relabels C-rows so that PV A-fragments are lane-local sacc regs (no P LDS round-trip).
// SPLIT: grid 1024 = 16 heads x 32 qtiles x 2 K-halves; partial (O,l) to workspace.
template <bool WS16, bool SPLIT>
__launch_bounds__(256, SPLIT ? 4 : 2)
__global__ void sdpa_kernel(const float* __restrict__ Qg, const float* __restrict__ Kg,
                            const float* __restrict__ Vg, const float* __restrict__ Mg,
                            const _Float16* __restrict__ Kh, const _Float16* __restrict__ Vth,
                            float* __restrict__ Og, float* __restrict__ Opart,
                            float* __restrict__ Lpart, const int* __restrict__ flag) {
  __shared__ __align__(16) _Float16 Ks[64 * 72];   // [key][feat]
  __shared__ __align__(16) _Float16 Vt[64 * 72];   // [feat][key]

  const int tid  = threadIdx.x;
  const int bid  = blockIdx.x;
  const int hh   = ((bid & 7) << 1) | ((bid >> 3) & 1);   // 2 heads per XCD (bid%8 -> XCD)
  const int half = SPLIT ? ((bid >> 4) & 1) : 0;
  const int qt   = SPLIT ? (bid >> 5) : (bid >> 4);
  const int w    = tid >> 6;
  const int lane = tid & 63;
  const int n    = lane & 31;
  const int h2   = lane >> 5;
  const int sig  = (n & 0x13) | ((n >> 1) & 4) | ((n << 1) & 8);  // swap bits 2,3
  const bool has_mask = (*flag) != 0;

  const size_t hoff = (size_t)hh * 4096 * 64;
  const int qcol = qt * 128 + w * 32 + n;
  const int ktlo = half * 32;
  const int ktn  = SPLIT ? 32 : 64;

  // ---- Q B-fragment straight from f32 (read once per block; no pre-convert pass) ----
  f16x8_t qf[4];
  {
    const float* qp = Qg + hoff + (size_t)qcol * 64 + 8 * h2;
#pragma unroll
    for (int kh = 0; kh < 4; ++kh) {
      f32x4_t a = *(const f32x4_t*)(qp + kh * 16);
      f32x4_t b = *(const f32x4_t*)(qp + kh * 16 + 4);
      union { _Float16 h[8]; f16x8_t v; } U;
#pragma unroll
      for (int j = 0; j < 4; ++j) { U.h[j] = (_Float16)(a[j] * QSCALE); U.h[4 + j] = (_Float16)(b[j] * QSCALE); }
      qf[kh] = U.v;
    }
  }

  f32x16_t o0 = {0.f,0.f,0.f,0.f,0.f,0.f,0.f,0.f,0.f,0.f,0.f,0.f,0.f,0.f,0.f,0.f};
  f32x16_t o1 = o0;
  float lacc = 0.0f;

#pragma unroll 1
  for (int kk = 0; kk < ktn; ++kk) {
    const int kt    = ktlo + kk;
    const int kbase = kt * 64;

    // -- staging prefetch (global -> regs) --
    uint4 kk0, kk1, vv0, vv1;            // WS16 path
    f32x4_t k0, k1, k2, k3;              // fallback K
    float vlo[8], vhi[8];                // fallback V
    if (WS16) {
      const _Float16* kp = Kh + hoff + (size_t)(kbase + (tid >> 2)) * 64 + (tid & 3) * 16;
      kk0 = *(const uint4*)(kp);
      kk1 = *(const uint4*)(kp + 8);
      const _Float16* vp = Vth + hoff + (size_t)(tid >> 2) * 4096 + kbase + (tid & 3) * 16;
      vv0 = *(const uint4*)(vp);
      vv1 = *(const uint4*)(vp + 8);
    } else {
      const float* kp = Kg + hoff + (size_t)(kbase + (tid >> 2)) * 64 + (tid & 3) * 16;
      k0 = *(const f32x4_t*)(kp + 0);
      k1 = *(const f32x4_t*)(kp + 4);
      k2 = *(const f32x4_t*)(kp + 8);
      k3 = *(const f32x4_t*)(kp + 12);
      const float* vp = Vg + hoff + (size_t)(kbase + (tid >> 5) * 8) * 64 + (tid & 31);
#pragma unroll
      for (int j = 0; j < 8; ++j) {
        vlo[j] = vp[(size_t)j * 64];
        vhi[j] = vp[(size_t)j * 64 + 32];
      }
    }

    // -- mask tile: element (kb, reg=8a+4b+c) -> key kb*32 + 16a + 8*h2 + 4b + c --
    f32x4_t mk[2][2][2];
    if (has_mask) {
      const float* mp = Mg + (size_t)qcol * 4096 + kbase + 8 * h2;
#pragma unroll
      for (int kb = 0; kb < 2; ++kb)
#pragma unroll
        for (int a = 0; a < 2; ++a)
#pragma unroll
          for (int b = 0; b < 2; ++b)
            mk[kb][a][b] = *(const f32x4_t*)(mp + kb * 32 + 16 * a + 4 * b);
    }

    __syncthreads();   // prior iteration's LDS reads complete before overwrite

    if (WS16) {
      *(uint4*)&Ks[(tid >> 2) * 72 + (tid & 3) * 16]     = kk0;
      *(uint4*)&Ks[(tid >> 2) * 72 + (tid & 3) * 16 + 8] = kk1;
      *(uint4*)&Vt[(tid >> 2) * 72 + (tid & 3) * 16]     = vv0;
      *(uint4*)&Vt[(tid >> 2) * 72 + (tid & 3) * 16 + 8] = vv1;
    } else {
      union { _Float16 h[8]; uint4 q; } A, B;
#pragma unroll
      for (int j = 0; j < 4; ++j) {
        A.h[j] = (_Float16)k0[j];  A.h[4 + j] = (_Float16)k1[j];
        B.h[j] = (_Float16)k2[j];  B.h[4 + j] = (_Float16)k3[j];
      }
      *(uint4*)&Ks[(tid >> 2) * 72 + (tid & 3) * 16]     = A.q;
      *(uint4*)&Ks[(tid >> 2) * 72 + (tid & 3) * 16 + 8] = B.q;
      union { _Float16 h[8]; uint4 q; } C, D;
#pragma unroll
      for (int j = 0; j < 8; ++j) { C.h[j] = (_Float16)vlo[j]; D.h[j] = (_Float16)vhi[j]; }
      *(uint4*)&Vt[(tid & 31) * 72 + (tid >> 5) * 8]        = C.q;
      *(uint4*)&Vt[((tid & 31) + 32) * 72 + (tid >> 5) * 8] = D.q;
    }

    __syncthreads();   // staging visible to all waves

#pragma unroll
    for (int kb = 0; kb < 2; ++kb) {
      // ---- S^T = K.Q^T with sigma-permuted A rows ----
      f32x16_t acc = {0.f,0.f,0.f,0.f,0.f,0.f,0.f,0.f,0.f,0.f,0.f,0.f,0.f,0.f,0.f,0.f};
#pragma unroll
      for (int kh = 0; kh < 4; ++kh) {
        const f16x8_t ka = *(const f16x8_t*)&Ks[(kb * 32 + sig) * 72 + kh * 16 + 8 * h2];
        acc = __builtin_amdgcn_mfma_f32_32x32x16_f16(ka, qf[kh], acc, 0, 0, 0);
      }
      // ---- softmax + PV, lane-local: frag f = 2*kb + a uses regs 8a..8a+7 ----
#pragma unroll
      for (int a = 0; a < 2; ++a) {
        union { _Float16 h[8]; f16x8_t v; f16x2_t p2[4]; } F;
#pragma unroll
        for (int idx = 0; idx < 8; ++idx) {
          float x = acc[8 * a + idx];
          if (has_mask) x = __builtin_fmaf(mk[kb][a][idx >> 2][idx & 3], LOG2E, x);
          F.h[idx] = (_Float16)EXP2F(x);
        }
#pragma unroll
        for (int t = 0; t < 4; ++t) lacc = rowsum2(F.p2[t], lacc);
        const int f = kb * 2 + a;
        const f16x8_t v0 = *(const f16x8_t*)&Vt[n * 72 + f * 16 + 8 * h2];
        o0 = __builtin_amdgcn_mfma_f32_32x32x16_f16(F.v, v0, o0, 0, 0, 0);
        const f16x8_t v1 = *(const f16x8_t*)&Vt[(32 + n) * 72 + f * 16 + 8 * h2];
        o1 = __builtin_amdgcn_mfma_f32_32x32x16_f16(F.v, v1, o1, 0, 0, 0);
      }
    }
  }

  // ---- epilogue ----
  float lq = lacc + __shfl_xor(lacc, 32);
  if constexpr (SPLIT) {
    // unnormalized partial O + per-row partial l
    float* op = Opart + (size_t)half * (16 * 4096 * 64) + hoff;
#pragma unroll
    for (int r2 = 0; r2 < 4; ++r2) {
#pragma unroll
      for (int rr = 0; rr < 4; ++rr) {
        const int reg  = r2 * 4 + rr;
        const int qrow = rr + 8 * r2 + 4 * h2;      // C/D row mapping (m74/m101)
        const size_t row = (size_t)(qt * 128 + w * 32 + qrow) * 64;
        op[row + n]      = o0[reg];
        op[row + 32 + n] = o1[reg];
      }
    }
    if (h2 == 0)
      Lpart[(size_t)half * 65536 + (size_t)hh * 4096 + qcol] = lq;
  } else {
    float* op = Og + hoff;
#pragma unroll
    for (int r2 = 0; r2 < 4; ++r2) {
#pragma unroll
      for (int rr = 0; rr < 4; ++rr) {
        const int reg  = r2 * 4 + rr;
        const int qrow = rr + 8 * r2 + 4 * h2;      // C/D row mapping (m74/m101)
        float lr  = __shfl(lq, qrow);
        float inv = 1.0f / lr;
        const size_t row = (size_t)(qt * 128 + w * 32 + qrow) * 64;
        op[row + n]      = o0[reg] * inv;
        op[row + 32 + n] = o1[reg] * inv;
      }
    }
  }
}

// ---------------- combine: O = (O0 + O1) / (l0 + l1) ----------------
__global__ void combine_kernel(const float* __restrict__ Opart, const float* __restrict__ Lpart,
                               float* __restrict__ Og) {
  const size_t e   = ((size_t)blockIdx.x * 256 + threadIdx.x) * 8;
  const size_t row = e >> 6;
  const float inv = 1.0f / (Lpart[row] + Lpart[65536 + row]);
  const float* a = Opart + e;
  const float* b = Opart + (size_t)16 * 4096 * 64 + e;
  f32x4_t x0 = *(const f32x4_t*)a,      x1 = *(const f32x4_t*)(a + 4);
  f32x4_t y0 = *(const f32x4_t*)b,      y1 = *(const f32x4_t*)(b + 4);
  f32x4_t r0, r1;
#pragma unroll
  for (int j = 0; j < 4; ++j) { r0[j] = (x0[j] + y0[j]) * inv; r1[j] = (x1[j] + y1[j]) * inv; }
  *(f32x4_t*)(Og + e)     = r0;
  *(f32x4_t*)(Og + e + 4) = r1;
}

extern "C" void kernel_launch(void* const* d_in, const int* in_sizes, int n_in,
                              void* d_out, int out_size, void* d_ws, size_t ws_size,
                              hipStream_t stream) {
  const float* Q = (const float*)d_in[0];
  const float* K = (const float*)d_in[1];
  const float* V = (const float*)d_in[2];
  const float* M = (const float*)d_in[3];
  float* O = (float*)d_out;

  const size_t NELEM = (size_t)16 * 4096 * 64;          // 4M per tensor
  const size_t need16    = 256 + 2 * NELEM * sizeof(_Float16);               // Kh + Vth
  const size_t needsplit = need16 + 2 * NELEM * sizeof(float)                // Opart (2 halves)
                                  + 2 * (size_t)65536 * sizeof(float);       // Lpart
  int* flag = (int*)d_ws;
  const bool ws16  = (ws_size >= need16);
  const bool split = (ws_size >= needsplit);
  _Float16* Kh    = ws16 ? (_Float16*)((char*)d_ws + 256) : nullptr;
  _Float16* Vth   = ws16 ? Kh + NELEM : nullptr;
  float*    Opart = split ? (float*)(Vth + NELEM) : nullptr;
  float*    Lpart = split ? Opart + 2 * NELEM : nullptr;

  hipMemsetAsync(flag, 0, sizeof(int), stream);
  prep_kernel<<<2048, 256, 0, stream>>>(M, K, V, Kh, Vth, flag);

  if (split) {
    sdpa_kernel<true, true><<<1024, 256, 0, stream>>>(Q, K, V, M, Kh, Vth, O, Opart, Lpart, flag);
    combine_kernel<<<2048, 256, 0, stream>>>(Opart, Lpart, O);
  } else if (ws16) {
    sdpa_kernel<true, false><<<512, 256, 0, stream>>>(Q, K, V, M, Kh, Vth, O, nullptr, nullptr, flag);
  } else {
    sdpa_kernel<false, false><<<512, 256, 0, stream>>>(Q, K, V, M, nullptr, nullptr, O, nullptr, nullptr, flag);
  }
}